// Round 7
// baseline (3427.902 us; speedup 1.0000x reference)
//
#include <hip/hip_runtime.h>

// ODE-GRU recurrence, B=128, L=2048, I=D=64.
// R10b: resubmit of R10 (previous bench died on infra, no data). Two batches
// per block, phase-interleaved. Wave-count series {2w:3137, 4w:2300, 8w:1935,
// 16w:2670 cy/step} shows a lockstep critical path ~2000cy that more waves
// cannot hide (shared barriers) and fewer waves fully expose. Fix: give the
// wave INDEPENDENT work to fill its own stalls — G=2 batches interleaved at
// the instruction level (R6's idea, but G=2 on the low-issue R9 quad
// structure instead of G=4 on the high-issue octet one):
//   phase1: round-1 (h -> t1) for batch A AND batch B; barrier;
//   phase2: round-2 (t1 -> h) for A AND B; barrier.
// 2 barriers per 2 batch-steps = 1 barrier/batch-step (halved); the two
// batches' LDS round trips and transcendental chains overlap in-wave.
// sh_out restored — R9's per-step global h-store forced a vmcnt(0) drain at
// the barrier (~300cy/step on the critical path).
// R10b hardening: per-batch pointers are named scalars (xsA/xsB...) so no
// runtime-indexed arrays can fall to scratch (methodology rule #20).
// Carried from R9: 4 waves (256 thr), quad-per-element (q=tid>>2, p=tid&3),
// dot16 + DPP quad reduce (cross-lane in-VALU), redundant per-quad gates (no
// exchange, no divergence), packed gx float4 {g0,g1,g2,dt}, no sh_x (gx phase
// reads x from global, L2-hot), gh linearity (M2=Whh@dw2, c2=Whh@db2).

#define NB    128
#define SEQ   2048
#define DIM   64
#define TILE  32
#define G     2
#define GXS   260   // sh_gx row stride (floats); rows hold [4q+{0,1,2}] + dt

typedef float f32x2 __attribute__((ext_vector_type(2)));

__device__ __forceinline__ float fast_rcp(float x) { return __builtin_amdgcn_rcpf(x); }

__device__ __forceinline__ float sigmoid_f(float v) {
    return fast_rcp(1.0f + __expf(-v));
}
__device__ __forceinline__ float tanh_f(float v) {
    float e = __expf(2.0f * v);
    return fmaf(-2.0f, fast_rcp(e + 1.0f), 1.0f);
}

template <int CTRL>
__device__ __forceinline__ float dpp_f(float v) {
    return __int_as_float(__builtin_amdgcn_mov_dpp(__float_as_int(v), CTRL, 0xF, 0xF, true));
}

// Butterfly sum over a lane-quad; every lane of the quad gets the total.
__device__ __forceinline__ float quad_reduce(float v) {
    v += dpp_f<0xB1>(v);
    v += dpp_f<0x4E>(v);
    return v;
}

// 16-element dot in packed fp32: 8 v_pk_fma_f32 + pk_add + add.
__device__ __forceinline__ float dot16p(const float4* w, const float4* h) {
    f32x2 a; a.x = 0.f; a.y = 0.f;
    f32x2 b; b.x = 0.f; b.y = 0.f;
#pragma unroll
    for (int i = 0; i < 4; i++) {
        f32x2 wlo; wlo.x = w[i].x; wlo.y = w[i].y;
        f32x2 whi; whi.x = w[i].z; whi.y = w[i].w;
        f32x2 hlo; hlo.x = h[i].x; hlo.y = h[i].y;
        f32x2 hhi; hhi.x = h[i].z; hhi.y = h[i].w;
        a = __builtin_elementwise_fma(wlo, hlo, a);
        b = __builtin_elementwise_fma(whi, hhi, b);
    }
    f32x2 s = a + b;
    return s.x + s.y;
}

// ---- prep: M2 = Whh @ dw2 (192x64), c2 = Whh @ db2 (192) ----
__global__ void odegru_prep(const float* __restrict__ w_hh,
                            const float* __restrict__ dw2,
                            const float* __restrict__ db2,
                            float* __restrict__ m2,   // 192*64
                            float* __restrict__ c2)   // 192
{
    const int idx = blockIdx.x * 256 + threadIdx.x;
    if (idx < 192 * 64) {
        const int r = idx >> 6, k = idx & 63;
        float s = 0.f;
#pragma unroll
        for (int j = 0; j < 64; j++) s = fmaf(w_hh[r * 64 + j], dw2[j * 64 + k], s);
        m2[idx] = s;
    }
    if (idx < 192) {
        float s = 0.f;
#pragma unroll
        for (int j = 0; j < 64; j++) s = fmaf(w_hh[idx * 64 + j], db2[j], s);
        c2[idx] = s;
    }
}

__global__ __launch_bounds__(256, 1)
void odegru_fused(const float* __restrict__ x,        // (B,L,I)
                  const float* __restrict__ tds,      // (B,L)
                  const int*   __restrict__ seq_lens, // (B)
                  const float* __restrict__ h0,       // (D)
                  const float* __restrict__ w_ih,     // (3D,I)
                  const float* __restrict__ w_hh,     // (3D,D)
                  const float* __restrict__ b_ih,     // (3D)
                  const float* __restrict__ b_hh,     // (3D)
                  const float* __restrict__ dw1,      // (D,D)
                  const float* __restrict__ db1,      // (D)
                  const float* __restrict__ dw2,      // (D,D)
                  const float* __restrict__ db2,      // (D)
                  const float* __restrict__ m2,       // (3D,D) = Whh@dw2
                  const float* __restrict__ c2,       // (3D)   = Whh@db2
                  float* __restrict__ out)            // (B,L,D) ++ (B,D)
{
    const int b0  = blockIdx.x * G;
    const int tid = threadIdx.x;      // 0..255
    const int q   = tid >> 2;         // owned element 0..63
    const int p   = tid & 3;          // K-chunk: [16p, 16p+16)

    const int slA = seq_lens[b0];
    const int slB = seq_lens[b0 + 1];

    __shared__ float sh_h  [G][DIM];
    __shared__ float sh_t1 [G][DIM];
    __shared__ float sh_gx [G][TILE][GXS];
    __shared__ float sh_out[G][TILE][DIM];

    // ---- persistent weights: 11 rows x 4 float4 = 176 VGPR (shared by G) ----
    float4 wU[4], w0[4], w1[4], w2[4], v0[4], v1[4], v2[4], vH[4];
    float4 wi0[4], wi1[4], wi2[4];
    const int r0 = q * 16 + p * 4;            // row q, chunk p (f4 units)
    const int r1 = (64 + q) * 16 + p * 4;     // row 64+q
    const int r2 = (128 + q) * 16 + p * 4;    // row 128+q
    {
        const float4* dw1v = (const float4*)dw1;
        const float4* dw2v = (const float4*)dw2;
        const float4* whhv = (const float4*)w_hh;
        const float4* m2v  = (const float4*)m2;
        const float4* wihv = (const float4*)w_ih;
#pragma unroll
        for (int i = 0; i < 4; i++) {
            wU[i]  = dw1v[r0 + i];    // u   = dw1_q @ h
            w0[i]  = whhv[r0 + i];    // G0  = Whh_q @ h
            w1[i]  = whhv[r1 + i];    // G1  = Whh_{64+q} @ h
            w2[i]  = whhv[r2 + i];    // G2  = Whh_{128+q} @ h
            v0[i]  = m2v [r0 + i];    // m0  = M2_q @ t1
            v1[i]  = m2v [r1 + i];    // m1  = M2_{64+q} @ t1
            v2[i]  = m2v [r2 + i];    // m2  = M2_{128+q} @ t1
            vH[i]  = dw2v[r0 + i];    // hot = dw2_q @ t1
            wi0[i] = wihv[r0 + i];    // gx rows
            wi1[i] = wihv[r1 + i];
            wi2[i] = wihv[r2 + i];
        }
    }
    const float db1q = db1[q];
    const float bh0 = b_hh[q], bh1 = b_hh[64 + q], bh2 = b_hh[128 + q];
    const float c0v = c2[q],   c1v = c2[64 + q],   c2n = c2[128 + q];
    const float db2q = db2[q];
    const float bx0 = b_ih[q], bx1 = b_ih[64 + q], bx2 = b_ih[128 + q];

    if (tid < DIM) {
        sh_h[0][tid] = h0[tid];
        sh_h[1][tid] = h0[tid];
    }

    // per-batch pointers as named scalars (no runtime-indexed arrays)
    const float4* xsA = (const float4*)(x + (size_t)b0 * SEQ * DIM);
    const float4* xsB = (const float4*)(x + (size_t)(b0 + 1) * SEQ * DIM);
    const float* tdA  = tds + (size_t)b0 * SEQ;
    const float* tdB  = tds + (size_t)(b0 + 1) * SEQ;
    float* outA = out + (size_t)b0 * SEQ * DIM;
    float* outB = out + (size_t)(b0 + 1) * SEQ * DIM;
    float* finA = out + (size_t)NB * SEQ * DIM + (size_t)b0 * DIM;
    float* finB = out + (size_t)NB * SEQ * DIM + (size_t)(b0 + 1) * DIM;

    for (int t0 = 0; t0 < SEQ; t0 += TILE) {
        // ---- gx phase, both batches interleaved per ts (loads of one batch
        //      in flight under the other's dots). No inner barriers. ----
        for (int ts = 0; ts < TILE; ts++) {
            const int t = t0 + ts;
            const bool liveA = (t < slA), liveB = (t < slB);
            float4 xa[4], xb4[4];
#pragma unroll
            for (int i = 0; i < 4; i++) {
                xa [i] = xsA[(size_t)t * 16 + 4 * p + i];
                xb4[i] = xsB[(size_t)t * 16 + 4 * p + i];
            }
            const float dtA = liveA ? tdA[t] : 0.0f;
            const float dtB = liveB ? tdB[t] : 0.0f;

            const float A0 = quad_reduce(dot16p(wi0, xa));
            const float A1 = quad_reduce(dot16p(wi1, xa));
            const float A2 = quad_reduce(dot16p(wi2, xa));
            const float B0 = quad_reduce(dot16p(wi0, xb4));
            const float B1 = quad_reduce(dot16p(wi1, xb4));
            const float B2 = quad_reduce(dot16p(wi2, xb4));
            if (p == 0) {
                float4 ga, gb;
                ga.x = liveA ? A0 + bx0 : bx0;   // masked x -> gx = b_ih
                ga.y = liveA ? A1 + bx1 : bx1;
                ga.z = liveA ? A2 + bx2 : bx2;
                ga.w = dtA;                      // masked dt -> 0
                gb.x = liveB ? B0 + bx0 : bx0;
                gb.y = liveB ? B1 + bx1 : bx1;
                gb.z = liveB ? B2 + bx2 : bx2;
                gb.w = dtB;
                *(float4*)&sh_gx[0][ts][4 * q] = ga;
                *(float4*)&sh_gx[1][ts][4 * q] = gb;
            }
        }
        __syncthreads();   // gx tiles + sh_h visible

#pragma unroll 1
        for (int ts = 0; ts < TILE; ts++) {
            const int t = t0 + ts;

            // ---- phase 1: round-1 (h -> t1) for BOTH batches ----
            const float4 gxA = *(const float4*)&sh_gx[0][ts][4 * q];
            const float4 gxB = *(const float4*)&sh_gx[1][ts][4 * q];
            const float  hqA = sh_h[0][q];
            const float  hqB = sh_h[1][q];

            const float4* hvA = (const float4*)sh_h[0];
            const float4* hvB = (const float4*)sh_h[1];
            float4 hA[4] = { hvA[4*p], hvA[4*p+1], hvA[4*p+2], hvA[4*p+3] };
            float4 hB[4] = { hvB[4*p], hvB[4*p+1], hvB[4*p+2], hvB[4*p+3] };

            const float sUA = quad_reduce(dot16p(wU, hA));
            const float sUB = quad_reduce(dot16p(wU, hB));
            const float s0A = quad_reduce(dot16p(w0, hA));
            const float s0B = quad_reduce(dot16p(w0, hB));
            const float s1A = quad_reduce(dot16p(w1, hA));
            const float s1B = quad_reduce(dot16p(w1, hB));
            const float s2A = quad_reduce(dot16p(w2, hA));
            const float s2B = quad_reduce(dot16p(w2, hB));
            const float t1A = tanh_f(sUA + db1q);
            const float t1B = tanh_f(sUB + db1q);
            if (p == 0) {
                sh_t1[0][q] = t1A;
                sh_t1[1][q] = t1B;
            }
            __syncthreads();   // t1 visible

            // ---- phase 2: round-2 (t1 -> h) for BOTH batches ----
            const float4* tvA = (const float4*)sh_t1[0];
            const float4* tvB = (const float4*)sh_t1[1];
            float4 tA[4] = { tvA[4*p], tvA[4*p+1], tvA[4*p+2], tvA[4*p+3] };
            float4 tB[4] = { tvB[4*p], tvB[4*p+1], tvB[4*p+2], tvB[4*p+3] };

            const float m0A  = quad_reduce(dot16p(v0, tA));
            const float m0B  = quad_reduce(dot16p(v0, tB));
            const float m1A  = quad_reduce(dot16p(v1, tA));
            const float m1B  = quad_reduce(dot16p(v1, tB));
            const float m2A  = quad_reduce(dot16p(v2, tA));
            const float m2B  = quad_reduce(dot16p(v2, tB));
            const float sHA  = quad_reduce(dot16p(vH, tA));
            const float sHB  = quad_reduce(dot16p(vH, tB));

            // gates, batch A
            {
                const float dtv = gxA.w;
                const float r   = sigmoid_f(gxA.x + s0A + fmaf(dtv, m0A + c0v, bh0));
                const float z   = sigmoid_f(gxA.y + s1A + fmaf(dtv, m1A + c1v, bh1));
                const float ghn = s2A + fmaf(dtv, m2A + c2n, bh2);
                const float n   = tanh_f(fmaf(r, ghn, gxA.z));
                const float ho  = fmaf(dtv, sHA + db2q, hqA);
                const float hn  = fmaf(z, ho - n, n);
                if (p == 0) {
                    sh_h[0][q] = hn;
                    sh_out[0][ts][q] = hn;
                    if (t == slA - 1) finA[q] = hn;   // rare: execz-skipped
                }
            }
            // gates, batch B
            {
                const float dtv = gxB.w;
                const float r   = sigmoid_f(gxB.x + s0B + fmaf(dtv, m0B + c0v, bh0));
                const float z   = sigmoid_f(gxB.y + s1B + fmaf(dtv, m1B + c1v, bh1));
                const float ghn = s2B + fmaf(dtv, m2B + c2n, bh2);
                const float n   = tanh_f(fmaf(r, ghn, gxB.z));
                const float ho  = fmaf(dtv, sHB + db2q, hqB);
                const float hn  = fmaf(z, ho - n, n);
                if (p == 0) {
                    sh_h[1][q] = hn;
                    sh_out[1][ts][q] = hn;
                    if (t == slB - 1) finB[q] = hn;
                }
            }
            __syncthreads();   // h visible
        }

        // ---- flush output tiles: 1024 f4 / 256 thr = 4 each ----
        {
            const float4* srcv = (const float4*)(&sh_out[0][0][0]);
            float4* dstA = (float4*)(outA + (size_t)t0 * DIM);
            float4* dstB = (float4*)(outB + (size_t)t0 * DIM);
#pragma unroll
            for (int k = 0; k < 2; k++) {
                dstA[tid + 256 * k] = srcv[tid + 256 * k];
                dstB[tid + 256 * k] = srcv[512 + tid + 256 * k];
            }
        }
        __syncthreads();
    }
}

extern "C" void kernel_launch(void* const* d_in, const int* in_sizes, int n_in,
                              void* d_out, int out_size, void* d_ws, size_t ws_size,
                              hipStream_t stream) {
    const float* x    = (const float*)d_in[0];
    const float* tds  = (const float*)d_in[1];
    const int*   sl   = (const int*)  d_in[2];
    const float* h0   = (const float*)d_in[3];
    const float* w_ih = (const float*)d_in[4];
    const float* w_hh = (const float*)d_in[5];
    const float* b_ih = (const float*)d_in[6];
    const float* b_hh = (const float*)d_in[7];
    const float* dw1  = (const float*)d_in[8];
    const float* db1  = (const float*)d_in[9];
    const float* dw2  = (const float*)d_in[10];
    const float* db2  = (const float*)d_in[11];
    float* out = (float*)d_out;

    float* m2 = (float*)d_ws;              // 192*64 floats
    float* c2 = m2 + 192 * 64;             // 192 floats

    odegru_prep<<<dim3(48), dim3(256), 0, stream>>>(w_hh, dw2, db2, m2, c2);
    odegru_fused<<<dim3(NB / G), dim3(256), 0, stream>>>(
        x, tds, sl, h0, w_ih, w_hh, b_ih, b_hh, dw1, db1, dw2, db2, m2, c2, out);
}

// Round 8
// 2686.918 us; speedup vs baseline: 1.2758x; 1.2758x over previous
//
#include <hip/hip_runtime.h>

// ODE-GRU recurrence, B=128, L=2048, I=D=64.
// R11: pin the weights, un-drain the barriers. R9/R10b showed VGPR_Count
// (124/144) < the 176 VGPRs of declared persistent weights: the compiler was
// re-loading weights from GLOBAL inside the step loop, and __syncthreads()
// (= s_waitcnt vmcnt(0) lgkmcnt(0) + s_barrier) drained those loads at every
// barrier — injecting vmem latency into the critical path twice per step in
// every round so far. Fixes, on the R9 4-wave quad structure:
//  1. Weights loaded as ext_vector f32x4 and PINNED via asm("":"+v"(reg)) —
//     asm-defined values cannot be rematerialized; ~260 VGPR @ 1 wave/SIMD.
//  2. lgkm-only barriers: s_waitcnt lgkmcnt(0) + s_barrier (HK pattern).
//     vmcnt never drained in the loop -> global ops stay in flight.
//  3. Therefore: h stored straight to global (fire-and-forget; sh_out and
//     flush phase deleted) and next-tile gx FUSED into the step loop with
//     software-pipelined x prefetch — independent VALU work fills the
//     ds_read/dep-chain stall windows; the serial gx phase disappears.
// Carried from R9: quad-per-element (q=tid>>2, p=tid&3), dot16 + DPP quad
// reduce (cross-lane in-VALU), redundant per-quad gates (no exchange, no
// divergence), packed gx float4 {g0,g1,g2,dt}, gh linearity (M2=Whh@dw2,
// c2=Whh@db2 in d_ws), masked x/dt semantics.

#define NB    128
#define SEQ   2048
#define DIM   64
#define TILE  32
#define GXS   260   // sh_gx row stride (floats)

typedef float f32x2 __attribute__((ext_vector_type(2)));
typedef float f32x4 __attribute__((ext_vector_type(4)));

__device__ __forceinline__ float fast_rcp(float x) { return __builtin_amdgcn_rcpf(x); }

__device__ __forceinline__ float sigmoid_f(float v) {
    return fast_rcp(1.0f + __expf(-v));
}
__device__ __forceinline__ float tanh_f(float v) {
    float e = __expf(2.0f * v);
    return fmaf(-2.0f, fast_rcp(e + 1.0f), 1.0f);
}

template <int CTRL>
__device__ __forceinline__ float dpp_f(float v) {
    return __int_as_float(__builtin_amdgcn_mov_dpp(__float_as_int(v), CTRL, 0xF, 0xF, true));
}

// Butterfly sum over a lane-quad; every lane of the quad gets the total.
__device__ __forceinline__ float quad_reduce(float v) {
    v += dpp_f<0xB1>(v);
    v += dpp_f<0x4E>(v);
    return v;
}

// 16-element dot in packed fp32: 8 v_pk_fma_f32 + pk_add + add.
__device__ __forceinline__ float dot16p(const f32x4* w, const f32x4* h) {
    f32x2 a; a.x = 0.f; a.y = 0.f;
    f32x2 b; b.x = 0.f; b.y = 0.f;
#pragma unroll
    for (int i = 0; i < 4; i++) {
        f32x2 wlo; wlo.x = w[i].x; wlo.y = w[i].y;
        f32x2 whi; whi.x = w[i].z; whi.y = w[i].w;
        f32x2 hlo; hlo.x = h[i].x; hlo.y = h[i].y;
        f32x2 hhi; hhi.x = h[i].z; hhi.y = h[i].w;
        a = __builtin_elementwise_fma(wlo, hlo, a);
        b = __builtin_elementwise_fma(whi, hhi, b);
    }
    f32x2 s = a + b;
    return s.x + s.y;
}

// Pin a 4-register f32x4 array into VGPRs (asm-defined => no remat/spill-by-reload).
#define PIN4(A) asm volatile("" : "+v"(A[0]), "+v"(A[1]), "+v"(A[2]), "+v"(A[3]))

// Workgroup barrier that waits ONLY lgkmcnt (LDS) — leaves global loads/stores
// in flight (no vmcnt drain, unlike __syncthreads()).
#define LGKM_BAR() do {                                        \
    asm volatile("s_waitcnt lgkmcnt(0)" ::: "memory");         \
    __builtin_amdgcn_s_barrier();                              \
    asm volatile("" ::: "memory");                             \
} while (0)

// ---- prep: M2 = Whh @ dw2 (192x64), c2 = Whh @ db2 (192) ----
__global__ void odegru_prep(const float* __restrict__ w_hh,
                            const float* __restrict__ dw2,
                            const float* __restrict__ db2,
                            float* __restrict__ m2,   // 192*64
                            float* __restrict__ c2)   // 192
{
    const int idx = blockIdx.x * 256 + threadIdx.x;
    if (idx < 192 * 64) {
        const int r = idx >> 6, k = idx & 63;
        float s = 0.f;
#pragma unroll
        for (int j = 0; j < 64; j++) s = fmaf(w_hh[r * 64 + j], dw2[j * 64 + k], s);
        m2[idx] = s;
    }
    if (idx < 192) {
        float s = 0.f;
#pragma unroll
        for (int j = 0; j < 64; j++) s = fmaf(w_hh[idx * 64 + j], db2[j], s);
        c2[idx] = s;
    }
}

__global__ __launch_bounds__(256, 1)
void odegru_fused(const float* __restrict__ x,        // (B,L,I)
                  const float* __restrict__ tds,      // (B,L)
                  const int*   __restrict__ seq_lens, // (B)
                  const float* __restrict__ h0,       // (D)
                  const float* __restrict__ w_ih,     // (3D,I)
                  const float* __restrict__ w_hh,     // (3D,D)
                  const float* __restrict__ b_ih,     // (3D)
                  const float* __restrict__ b_hh,     // (3D)
                  const float* __restrict__ dw1,      // (D,D)
                  const float* __restrict__ db1,      // (D)
                  const float* __restrict__ dw2,      // (D,D)
                  const float* __restrict__ db2,      // (D)
                  const float* __restrict__ m2,       // (3D,D) = Whh@dw2
                  const float* __restrict__ c2,       // (3D)   = Whh@db2
                  float* __restrict__ out)            // (B,L,D) ++ (B,D)
{
    const int b   = blockIdx.x;
    const int tid = threadIdx.x;      // 0..255
    const int q   = tid >> 2;         // owned element 0..63
    const int p   = tid & 3;          // K-chunk: [16p, 16p+16)
    const int seqlen = seq_lens[b];

    __shared__ float sh_h [DIM];
    __shared__ float sh_t1[DIM];
    __shared__ float sh_gx[2][TILE][GXS];

    // ---- persistent weights: 11 rows x 4 f32x4 = 176 VGPR, asm-pinned ----
    f32x4 wU[4], w0[4], w1[4], w2[4], v0[4], v1[4], v2[4], vH[4];
    f32x4 wi0[4], wi1[4], wi2[4];
    const int r0 = q * 16 + p * 4;            // row q, chunk p (f4 units)
    const int r1 = (64 + q) * 16 + p * 4;     // row 64+q
    const int r2 = (128 + q) * 16 + p * 4;    // row 128+q
    {
        const f32x4* dw1v = (const f32x4*)dw1;
        const f32x4* dw2v = (const f32x4*)dw2;
        const f32x4* whhv = (const f32x4*)w_hh;
        const f32x4* m2v  = (const f32x4*)m2;
        const f32x4* wihv = (const f32x4*)w_ih;
#pragma unroll
        for (int i = 0; i < 4; i++) {
            wU[i]  = dw1v[r0 + i];    // u   = dw1_q @ h
            w0[i]  = whhv[r0 + i];    // G0  = Whh_q @ h
            w1[i]  = whhv[r1 + i];    // G1  = Whh_{64+q} @ h
            w2[i]  = whhv[r2 + i];    // G2  = Whh_{128+q} @ h
            v0[i]  = m2v [r0 + i];    // m0  = M2_q @ t1
            v1[i]  = m2v [r1 + i];    // m1  = M2_{64+q} @ t1
            v2[i]  = m2v [r2 + i];    // m2  = M2_{128+q} @ t1
            vH[i]  = dw2v[r0 + i];    // hot = dw2_q @ t1
            wi0[i] = wihv[r0 + i];    // gx rows
            wi1[i] = wihv[r1 + i];
            wi2[i] = wihv[r2 + i];
        }
        PIN4(wU); PIN4(w0); PIN4(w1); PIN4(w2);
        PIN4(v0); PIN4(v1); PIN4(v2); PIN4(vH);
        PIN4(wi0); PIN4(wi1); PIN4(wi2);
    }
    float db1q = db1[q];
    float bh0 = b_hh[q], bh1 = b_hh[64 + q], bh2 = b_hh[128 + q];
    float c0v = c2[q],   c1v = c2[64 + q],   c2n = c2[128 + q];
    float db2q = db2[q];
    float bx0 = b_ih[q], bx1 = b_ih[64 + q], bx2 = b_ih[128 + q];
    asm volatile("" : "+v"(db1q), "+v"(bh0), "+v"(bh1), "+v"(bh2),
                      "+v"(c0v), "+v"(c1v), "+v"(c2n), "+v"(db2q),
                      "+v"(bx0), "+v"(bx1), "+v"(bx2));

    if (tid < DIM) sh_h[tid] = h0[tid];

    const float*  xb   = x   + (size_t)b * SEQ * DIM;
    const float*  tdb  = tds + (size_t)b * SEQ;
    float* outb = out + (size_t)b * SEQ * DIM;
    float* finb = out + (size_t)NB * SEQ * DIM + (size_t)b * DIM;
    const f32x4* xsrc = (const f32x4*)xb;

    // ---- prologue: gx for tile 0 ----
    for (int ts = 0; ts < TILE; ts++) {
        f32x4 x4[4];
#pragma unroll
        for (int i = 0; i < 4; i++) x4[i] = xsrc[(size_t)ts * 16 + 4 * p + i];
        const bool live = (ts < seqlen);
        const float dtv = live ? tdb[ts] : 0.0f;
        const float A0 = quad_reduce(dot16p(wi0, x4));
        const float A1 = quad_reduce(dot16p(wi1, x4));
        const float A2 = quad_reduce(dot16p(wi2, x4));
        if (p == 0) {
            f32x4 gxw;
            gxw.x = live ? A0 + bx0 : bx0;
            gxw.y = live ? A1 + bx1 : bx1;
            gxw.z = live ? A2 + bx2 : bx2;
            gxw.w = dtv;
            *(f32x4*)&sh_gx[0][ts][4 * q] = gxw;
        }
    }
    __syncthreads();   // full drain once; sh_h + sh_gx[0] visible

    for (int t0 = 0; t0 < SEQ; t0 += TILE) {
        const int  cur = (t0 >> 5) & 1;
        const int  nxt = cur ^ 1;
        const bool have_next = (t0 + TILE) < SEQ;

        // prefetch x for next tile's ts=0 (stays in flight across barriers)
        f32x4 xc[4];
        if (have_next) {
#pragma unroll
            for (int i = 0; i < 4; i++)
                xc[i] = xsrc[(size_t)(t0 + TILE) * 16 + 4 * p + i];
        }

#pragma unroll 1
        for (int ts = 0; ts < TILE; ts++) {
            const int t = t0 + ts;

            // ---- prefetch: gx b128 + hq (independent LDS reads) ----
            const f32x4 gx4 = *(const f32x4*)&sh_gx[cur][ts][4 * q];
            const float hq  = sh_h[q];

            // ---- Round 1 (read h chunk): 4 dot16 + quad reduces ----
            const f32x4* hv = (const f32x4*)sh_h;
            f32x4 h4[4] = { hv[4*p], hv[4*p+1], hv[4*p+2], hv[4*p+3] };
            const float sU = quad_reduce(dot16p(wU, h4));
            const float s0 = quad_reduce(dot16p(w0, h4));
            const float s1 = quad_reduce(dot16p(w1, h4));
            const float s2 = quad_reduce(dot16p(w2, h4));

            // ---- fused gx for next tile, step ts (independent work that
            //      fills R1's latency; x loads never drained by barriers) ----
            f32x4 xn[4];
            if (have_next) {
                const int tn = t0 + TILE + ts;
                if (ts + 1 < TILE) {
#pragma unroll
                    for (int i = 0; i < 4; i++)
                        xn[i] = xsrc[(size_t)(tn + 1) * 16 + 4 * p + i];
                }
                const bool nlive = (tn < seqlen);
                const float ndt  = nlive ? tdb[tn] : 0.0f;
                const float A0 = quad_reduce(dot16p(wi0, xc));
                const float A1 = quad_reduce(dot16p(wi1, xc));
                const float A2 = quad_reduce(dot16p(wi2, xc));
                if (p == 0) {
                    f32x4 gxw;
                    gxw.x = nlive ? A0 + bx0 : bx0;
                    gxw.y = nlive ? A1 + bx1 : bx1;
                    gxw.z = nlive ? A2 + bx2 : bx2;
                    gxw.w = ndt;
                    *(f32x4*)&sh_gx[nxt][ts][4 * q] = gxw;
                }
            }

            const float t1v = tanh_f(sU + db1q);
            if (p == 0) sh_t1[q] = t1v;
            LGKM_BAR();   // t1 visible; vmem stays in flight

            // ---- Round 2 (read t1 chunk): 4 dot16 + quad reduces ----
            const f32x4* tv = (const f32x4*)sh_t1;
            f32x4 t4[4] = { tv[4*p], tv[4*p+1], tv[4*p+2], tv[4*p+3] };
            const float m0  = quad_reduce(dot16p(v0, t4));
            const float m1  = quad_reduce(dot16p(v1, t4));
            const float m2s = quad_reduce(dot16p(v2, t4));
            const float sH  = quad_reduce(dot16p(vH, t4));

            // ---- gates: redundant per quad (no exchange, no divergence) ----
            const float dtv = gx4.w;
            const float r   = sigmoid_f(gx4.x + s0 + fmaf(dtv, m0 + c0v, bh0));
            const float z   = sigmoid_f(gx4.y + s1 + fmaf(dtv, m1 + c1v, bh1));
            const float ghn = s2 + fmaf(dtv, m2s + c2n, bh2);
            const float n   = tanh_f(fmaf(r, ghn, gx4.z));
            const float ho  = fmaf(dtv, sH + db2q, hq);
            const float hn  = fmaf(z, ho - n, n);   // (1-z)*n + z*ho
            if (p == 0) {
                sh_h[q] = hn;
                outb[(size_t)t * DIM + q] = hn;     // fire-and-forget
                if (t == seqlen - 1) finb[q] = hn;  // rare, in flight
            }
            LGKM_BAR();   // h visible; vmem stays in flight

#pragma unroll
            for (int i = 0; i < 4; i++) xc[i] = xn[i];
        }
    }
}

extern "C" void kernel_launch(void* const* d_in, const int* in_sizes, int n_in,
                              void* d_out, int out_size, void* d_ws, size_t ws_size,
                              hipStream_t stream) {
    const float* x    = (const float*)d_in[0];
    const float* tds  = (const float*)d_in[1];
    const int*   sl   = (const int*)  d_in[2];
    const float* h0   = (const float*)d_in[3];
    const float* w_ih = (const float*)d_in[4];
    const float* w_hh = (const float*)d_in[5];
    const float* b_ih = (const float*)d_in[6];
    const float* b_hh = (const float*)d_in[7];
    const float* dw1  = (const float*)d_in[8];
    const float* db1  = (const float*)d_in[9];
    const float* dw2  = (const float*)d_in[10];
    const float* db2  = (const float*)d_in[11];
    float* out = (float*)d_out;

    float* m2 = (float*)d_ws;              // 192*64 floats
    float* c2 = m2 + 192 * 64;             // 192 floats

    odegru_prep<<<dim3(48), dim3(256), 0, stream>>>(w_hh, dw2, db2, m2, c2);
    odegru_fused<<<dim3(NB), dim3(256), 0, stream>>>(
        x, tds, sl, h0, w_ih, w_hh, b_ih, b_hh, dw1, db1, dw2, db2, m2, c2, out);
}

// Round 9
// 1685.393 us; speedup vs baseline: 2.0339x; 1.5942x over previous
//
#include <hip/hip_runtime.h>

// ODE-GRU recurrence, B=128, L=2048, I=D=64.
// R12: force TRUE weight residency on the best structure (R5, 1671us).
// Discovery chain: R9/R10b/R11 all show VGPR_Count << declared persistent
// weight footprint (R5: 84 vs 112; R9: 124 vs 176; R11 pins-at-init: 136) —
// the compiler rematerializes weight loads from global INSIDE the step loop,
// and __syncthreads' vmcnt(0) drain serializes those ~200cy L2 reloads onto
// the critical path every step. This is the unexplained ~900cy/step stall
// that survived every restructure (R6-R11), because every restructure
// carried the same remat bug.
// Fix: asm volatile("" : "+v"(w)) executed EVERY loop iteration — the weight
// register becomes a loop-carried def/use chain through the asm, so remat
// from global can no longer satisfy it; values must stay in VGPRs.
// (R11's PIN-at-init failed because it only forces materialization once.)
// Everything else is byte-for-byte R5: 8 waves (512 thr), octet-per-element
// (quad A/B roles), 2 barriers/step, gh linearity (M2=Whh@dw2, c2=Whh@db2),
// packed-fp32 dot16, DPP quad butterflies + octet swap for n, gx tile
// precompute, LDS sh_out buffered flush (no in-loop vmem except the one
// finb store per sequence).

#define NB    128
#define SEQ   2048
#define DIM   64
#define TILE  32
#define XS    68     // sh_x row stride (floats)
#define GS    200    // sh_gx row stride (floats)

typedef float f32x2 __attribute__((ext_vector_type(2)));
typedef float f32x4 __attribute__((ext_vector_type(4)));

__device__ __forceinline__ float fast_rcp(float x) { return __builtin_amdgcn_rcpf(x); }

__device__ __forceinline__ float sigmoid_f(float v) {
    return fast_rcp(1.0f + __expf(-v));
}
__device__ __forceinline__ float tanh_f(float v) {
    float e = __expf(2.0f * v);
    return fmaf(-2.0f, fast_rcp(e + 1.0f), 1.0f);
}

template <int CTRL>
__device__ __forceinline__ float dpp_f(float v) {
    return __int_as_float(__builtin_amdgcn_mov_dpp(__float_as_int(v), CTRL, 0xF, 0xF, true));
}

// Butterfly sum over a lane-quad; every lane of the quad gets the total.
__device__ __forceinline__ float quad_reduce(float v) {
    v += dpp_f<0xB1>(v);
    v += dpp_f<0x4E>(v);
    return v;
}

// Swap values between the two quads of each 8-lane octet (row_half_mirror).
__device__ __forceinline__ float octet_swap(float v) {
    return dpp_f<0x141>(v);
}

// 16-element dot in packed fp32: 8 v_pk_fma_f32 + pk_add + add.
__device__ __forceinline__ float dot16p(const f32x4* w, const f32x4* h) {
    f32x2 a; a.x = 0.f; a.y = 0.f;
    f32x2 b; b.x = 0.f; b.y = 0.f;
#pragma unroll
    for (int i = 0; i < 4; i++) {
        f32x2 wlo; wlo.x = w[i].x; wlo.y = w[i].y;
        f32x2 whi; whi.x = w[i].z; whi.y = w[i].w;
        f32x2 hlo; hlo.x = h[i].x; hlo.y = h[i].y;
        f32x2 hhi; hhi.x = h[i].z; hhi.y = h[i].w;
        a = __builtin_elementwise_fma(wlo, hlo, a);
        b = __builtin_elementwise_fma(whi, hhi, b);
    }
    f32x2 s = a + b;
    return s.x + s.y;
}

// Loop-carried register pin: executed per iteration, forces residency.
#define PINA4(A) asm volatile("" : "+v"(A[0]), "+v"(A[1]), "+v"(A[2]), "+v"(A[3]))

// ---- prep: M2 = Whh @ dw2 (192x64), c2 = Whh @ db2 (192) ----
__global__ void odegru_prep(const float* __restrict__ w_hh,
                            const float* __restrict__ dw2,
                            const float* __restrict__ db2,
                            float* __restrict__ m2,   // 192*64
                            float* __restrict__ c2)   // 192
{
    const int idx = blockIdx.x * 256 + threadIdx.x;
    if (idx < 192 * 64) {
        const int r = idx >> 6, k = idx & 63;
        float s = 0.f;
#pragma unroll
        for (int j = 0; j < 64; j++) s = fmaf(w_hh[r * 64 + j], dw2[j * 64 + k], s);
        m2[idx] = s;
    }
    if (idx < 192) {
        float s = 0.f;
#pragma unroll
        for (int j = 0; j < 64; j++) s = fmaf(w_hh[idx * 64 + j], db2[j], s);
        c2[idx] = s;
    }
}

__global__ __launch_bounds__(512, 2)
void odegru_fused(const float* __restrict__ x,        // (B,L,I)
                  const float* __restrict__ tds,      // (B,L)
                  const int*   __restrict__ seq_lens, // (B)
                  const float* __restrict__ h0,       // (D)
                  const float* __restrict__ w_ih,     // (3D,I)
                  const float* __restrict__ w_hh,     // (3D,D)
                  const float* __restrict__ b_ih,     // (3D)
                  const float* __restrict__ b_hh,     // (3D)
                  const float* __restrict__ dw1,      // (D,D)
                  const float* __restrict__ db1,      // (D)
                  const float* __restrict__ dw2,      // (D,D)
                  const float* __restrict__ db2,      // (D)
                  const float* __restrict__ m2,       // (3D,D) = Whh@dw2
                  const float* __restrict__ c2,       // (3D)   = Whh@db2
                  float* __restrict__ out)            // (B,L,D) ++ (B,D)
{
    const int b   = blockIdx.x;
    const int tid = threadIdx.x;
    const int q8  = tid >> 3;         // octet = element 0..63
    const int p   = tid & 3;          // K-chunk within quad: [16p,16p+16)
    const bool qb = (tid & 4) != 0;   // quad B of the octet
    const int seqlen = seq_lens[b];

    __shared__ float sh_h [DIM];
    __shared__ float sh_t1[DIM];
    __shared__ float sh_x [TILE][XS];
    __shared__ float sh_gx[TILE][GS];
    __shared__ float sh_dt[TILE];
    __shared__ float sh_out[TILE][DIM];

    // ---- persistent weights: 4 dot-rows (64 floats) + 3 gx-rows (48) ----
    f32x4 wA[4], wB[4], wC[4], wD[4], wi0[4], wi1[4], wi2[4];
    {
        const f32x4* dw1v = (const f32x4*)dw1;
        const f32x4* dw2v = (const f32x4*)dw2;
        const f32x4* whhv = (const f32x4*)w_hh;
        const f32x4* m2v  = (const f32x4*)m2;
        const f32x4* wihv = (const f32x4*)w_ih;
        const int c = p * 4;
        if (!qb) {
#pragma unroll
            for (int i = 0; i < 4; i++) {
                wA[i] = dw1v[q8 * 16 + c + i];            // u    = dw1_q @ h
                wB[i] = whhv[(64 + q8) * 16 + c + i];     // G1   = Whh_{64+q} @ h
                wC[i] = m2v [(64 + q8) * 16 + c + i];     // m1   = M2_{64+q} @ t1
                wD[i] = dw2v[q8 * 16 + c + i];            // hot  = dw2_q @ t1
            }
        } else {
#pragma unroll
            for (int i = 0; i < 4; i++) {
                wA[i] = whhv[q8 * 16 + c + i];            // G0   = Whh_q @ h
                wB[i] = whhv[(128 + q8) * 16 + c + i];    // G2   = Whh_{128+q} @ h
                wC[i] = m2v [q8 * 16 + c + i];            // m0   = M2_q @ t1
                wD[i] = m2v [(128 + q8) * 16 + c + i];    // m2   = M2_{128+q} @ t1
            }
        }
        // gx precompute rows (quad qg = (tid>>2)&63)
        const int qg = (tid >> 2) & 63;
#pragma unroll
        for (int i = 0; i < 4; i++) {
            wi0[i] = wihv[(qg)       * 16 + c + i];
            wi1[i] = wihv[(64 + qg)  * 16 + c + i];
            wi2[i] = wihv[(128 + qg) * 16 + c + i];
        }
    }
    // biases: quad A: {db1_q, bh1, c1, db2_q}; quad B: {bh0, c0, bh2, c2n}
    float fA, fB, fC, fD;
    if (!qb) { fA = db1[q8];      fB = b_hh[64 + q8];  fC = c2[64 + q8];    fD = db2[q8]; }
    else     { fA = b_hh[q8];     fB = c2[q8];         fC = b_hh[128 + q8]; fD = c2[128 + q8]; }
    const int qg = (tid >> 2) & 63;
    float rbx0 = b_ih[qg], rbx1 = b_ih[64 + qg], rbx2 = b_ih[128 + qg];

    if (tid < DIM) sh_h[tid] = h0[tid];

    const float* xb  = x   + (size_t)b * SEQ * DIM;
    const float* tdb = tds + (size_t)b * SEQ;
    float* outb = out + (size_t)b * SEQ * DIM;
    float* finb = out + (size_t)NB * SEQ * DIM + (size_t)b * DIM;

    for (int t0 = 0; t0 < SEQ; t0 += TILE) {
        // ---- stage x tile (masked) + dt tile (masked); 512 f4 = 1/thread ----
        {
            const float4* src = (const float4*)(xb + (size_t)t0 * DIM);
            const int ts0 = tid >> 4, j = tid & 15;
            float4 v = src[tid];
            if (t0 + ts0 >= seqlen) v = make_float4(0.f, 0.f, 0.f, 0.f);
            *(float4*)&sh_x[ts0][4 * j] = v;
            if (tid < TILE) {
                const int t = t0 + tid;
                sh_dt[tid] = (t < seqlen) ? tdb[t] : 0.0f;
            }
        }
        __syncthreads();

        // ---- gx tile: rows {qg,64+qg,128+qg}; lower half even ts, upper odd ----
        {
            const int c = p * 4;
            for (int ts = (tid >= 256) ? 1 : 0; ts < TILE; ts += 2) {
                // loop-carried pin: gx weights must stay in VGPRs
                PINA4(wi0); PINA4(wi1); PINA4(wi2);
                asm volatile("" : "+v"(rbx0), "+v"(rbx1), "+v"(rbx2));
                const f32x4* xv = (const f32x4*)&sh_x[ts][0];
                f32x4 x4[4] = { xv[c], xv[c + 1], xv[c + 2], xv[c + 3] };
                float A0 = quad_reduce(dot16p(wi0, x4));
                float A1 = quad_reduce(dot16p(wi1, x4));
                float A2 = quad_reduce(dot16p(wi2, x4));
                if (p == 0) {
                    sh_gx[ts][qg]       = A0 + rbx0;
                    sh_gx[ts][64 + qg]  = A1 + rbx1;
                    sh_gx[ts][128 + qg] = A2 + rbx2;
                }
            }
        }
        __syncthreads();

#pragma unroll 1
        for (int ts = 0; ts < TILE; ts++) {
            const int t = t0 + ts;

            // loop-carried pin: recurrence weights + biases must stay in VGPRs
            PINA4(wA); PINA4(wB); PINA4(wC); PINA4(wD);
            asm volatile("" : "+v"(fA), "+v"(fB), "+v"(fC), "+v"(fD));

            // ---- prefetch (independent LDS reads) ----
            const float dtv = sh_dt[ts];
            float gA, gB = 0.f, hq = 0.f;
            if (!qb) { gA = sh_gx[ts][64 + q8]; hq = sh_h[q8]; }       // gx1
            else     { gA = sh_gx[ts][q8];      gB = sh_gx[ts][128 + q8]; } // gx0, gx2

            // ---- Round 1 (read h): 2 dots/lane ----
            const f32x4* hv = (const f32x4*)sh_h;
            f32x4 h4[4] = { hv[4*p], hv[4*p+1], hv[4*p+2], hv[4*p+3] };
            const float sA = quad_reduce(dot16p(wA, h4));  // A: u   | B: G0
            const float sB = quad_reduce(dot16p(wB, h4));  // A: G1  | B: G2
            if (!qb) {
                const float t1v = tanh_f(sA + fA);
                if (p == 0) sh_t1[q8] = t1v;
            }
            __syncthreads();   // t1 visible

            // ---- Round 2 (read t1): 2 dots/lane + finish ----
            const f32x4* tv = (const f32x4*)sh_t1;
            f32x4 t4[4] = { tv[4*p], tv[4*p+1], tv[4*p+2], tv[4*p+3] };
            const float sC = quad_reduce(dot16p(wC, t4));  // A: m1  | B: m0
            const float sD = quad_reduce(dot16p(wD, t4));  // A: hot | B: m2
            float val, z = 0.f, ho = 0.f;
            if (!qb) {
                z   = sigmoid_f(gA + sB + fmaf(dtv, sC + fC, fB));     // z-gate
                ho  = fmaf(dtv, sD + fD, hq);                          // h_ode
                val = 0.f;
            } else {
                const float r   = sigmoid_f(gA + sA + fmaf(dtv, sC + fB, fA));
                const float ghn = sB + fmaf(dtv, sD + fD, fC);
                val = tanh_f(fmaf(r, ghn, gB));                        // n
            }
            const float n = octet_swap(val);   // quad A receives n from quad B
            if (!qb) {
                const float hn = fmaf(z, ho - n, n);   // (1-z)*n + z*ho
                if (p == 0) {
                    sh_h[q8] = hn;
                    sh_out[ts][q8] = hn;
                    if (t == seqlen - 1) finb[q8] = hn;
                }
            }
            __syncthreads();   // h visible
        }

        // ---- flush output tile: 512 float4 = 1/thread ----
        {
            float4* dst = (float4*)(outb + (size_t)t0 * DIM);
            const float4* srcv = (const float4*)(&sh_out[0][0]);
            dst[tid] = srcv[tid];
        }
    }
}

extern "C" void kernel_launch(void* const* d_in, const int* in_sizes, int n_in,
                              void* d_out, int out_size, void* d_ws, size_t ws_size,
                              hipStream_t stream) {
    const float* x    = (const float*)d_in[0];
    const float* tds  = (const float*)d_in[1];
    const int*   sl   = (const int*)  d_in[2];
    const float* h0   = (const float*)d_in[3];
    const float* w_ih = (const float*)d_in[4];
    const float* w_hh = (const float*)d_in[5];
    const float* b_ih = (const float*)d_in[6];
    const float* b_hh = (const float*)d_in[7];
    const float* dw1  = (const float*)d_in[8];
    const float* db1  = (const float*)d_in[9];
    const float* dw2  = (const float*)d_in[10];
    const float* db2  = (const float*)d_in[11];
    float* out = (float*)d_out;

    float* m2 = (float*)d_ws;              // 192*64 floats
    float* c2 = m2 + 192 * 64;             // 192 floats

    odegru_prep<<<dim3(48), dim3(256), 0, stream>>>(w_hh, dw2, db2, m2, c2);
    odegru_fused<<<dim3(NB), dim3(512), 0, stream>>>(
        x, tds, sl, h0, w_ih, w_hh, b_ih, b_hh, dw1, db1, dw2, db2, m2, c2, out);
}